// Round 10
// baseline (3997.606 us; speedup 1.0000x reference)
//
#include <hip/hip_runtime.h>
#include <math.h>

typedef __attribute__((ext_vector_type(8))) short short8v;   // 8 bf16
typedef __attribute__((ext_vector_type(4))) float f32x4;     // 4 f32 acc

constexpr int Bn = 64;
constexpr int Tn = 512;
constexpr int Hn = 768;
constexpr int RTn = Bn * Tn;               // 32768 rows

constexpr int NPROD = 24;                  // col-blocks per group
constexpr int NGRP  = 8;                   // batch groups (8 batches each)
constexpr int SLOTS = 4;                   // publish ring depth
constexpr int GSTR  = NPROD * 512;         // floats per group per slot (=6144 u64)
constexpr int SSTR  = NGRP * GSTR;         // floats per slot
constexpr int PITCH = 792;                 // plane row pitch (ushorts), 768+24 pad
constexpr int PSZ   = 16 * PITCH;          // plane size (ushorts) = 12672

// workspace offsets (in floats)
constexpr size_t OFF_XP    = 0;
constexpr size_t OFF_H12   = OFF_XP  + (size_t)RTn * Hn;
constexpr size_t OFF_TAGX  = OFF_H12 + (size_t)RTn * Hn;
constexpr size_t OFF_C12   = OFF_TAGX + (size_t)RTn;
constexpr size_t OFF_PUB   = OFF_C12  + Hn;

__device__ inline unsigned short f2bf(float f) {
    union { float f; unsigned u; } v{f};
    unsigned r = v.u + 0x7FFF + ((v.u >> 16) & 1);   // RNE
    return (unsigned short)(r >> 16);
}
__device__ inline float bf2f(unsigned short h) {
    union { unsigned u; float f; } v; v.u = ((unsigned)h) << 16; return v.f;
}
__device__ inline unsigned f24(float f) {            // RNE fp32 -> top 24 bits
    union { float f; unsigned u; } v{f};
    unsigned r = v.u + 0x7F + ((v.u >> 8) & 1);
    return r >> 8;
}
__device__ inline float bf24(unsigned b) {           // 24-bit -> fp32
    union { unsigned u; float f; } v; v.u = b << 8; return v.f;
}

// ---------------------------------------------------------------------------
__global__ void __launch_bounds__(256) c12_kernel(const float* __restrict__ Whh12,
                                                  const float* __restrict__ hinit,
                                                  const float* __restrict__ b12,
                                                  float* __restrict__ c12) {
    int j = blockIdx.x * 256 + threadIdx.x;
    if (j >= Hn) return;
    float s = b12[j];
    const float* row = Whh12 + (size_t)j * Hn;
    for (int e = 0; e < Hn; ++e) s += row[e] * hinit[e];
    c12[j] = s;
}

// ---------------------------------------------------------------------------
__global__ void __launch_bounds__(256) tagx_kernel(const float* __restrict__ bert,
                                                   const float* __restrict__ Wtag,
                                                   const float* __restrict__ btag,
                                                   float* __restrict__ tagx) {
    int r = blockIdx.x * 4 + (threadIdx.x >> 6);
    int lane = threadIdx.x & 63;
    const float* wx = Wtag + 2 * Hn;
    const float* row = bert + (size_t)r * Hn;
    float s = 0.f;
    for (int e = lane; e < Hn; e += 64) s += row[e] * wx[e];
    #pragma unroll
    for (int m = 1; m < 64; m <<= 1) s += __shfl_xor(s, m, 64);
    if (lane == 0) tagx[r] = s + btag[0];
}

// ---------------------------------------------------------------------------
// Precompute GEMM (fp32): xp11 and tanh'ed h12_seq.
__global__ void __launch_bounds__(256) gemm_pre(const float* __restrict__ bert,
                                                const float* __restrict__ Wih11,
                                                const float* __restrict__ Wih12,
                                                const float* __restrict__ b11,
                                                const float* __restrict__ c12,
                                                float* __restrict__ xp,
                                                float* __restrict__ h12) {
    constexpr int BM = 128, BN = 64, BK = 16;
    __shared__ float As[BK][BM];
    __shared__ float Ws[BK][BN];
    const int bid = blockIdx.x;
    const int mt = bid / 24, nt = bid % 24;
    const int r0 = mt * BM;
    const int n0 = nt * BN;
    const bool second = (n0 >= Hn);
    const float* W = second ? Wih12 : Wih11;
    const int jbase = second ? (n0 - Hn) : n0;
    const int tid = threadIdx.x;
    const int ty = tid >> 4, tx = tid & 15;
    const int lrow = tid >> 1, lhalf = (tid & 1) * 8;
    const int wjl = tid & 63, wkk = tid >> 6;
    float acc[8][4] = {};
    for (int e0 = 0; e0 < Hn; e0 += BK) {
        float4 av0 = *(const float4*)(bert + (size_t)(r0 + lrow) * Hn + e0 + lhalf);
        float4 av1 = *(const float4*)(bert + (size_t)(r0 + lrow) * Hn + e0 + lhalf + 4);
        float4 wv  = *(const float4*)(W + (size_t)(jbase + wjl) * Hn + e0 + wkk * 4);
        As[lhalf + 0][lrow] = av0.x; As[lhalf + 1][lrow] = av0.y;
        As[lhalf + 2][lrow] = av0.z; As[lhalf + 3][lrow] = av0.w;
        As[lhalf + 4][lrow] = av1.x; As[lhalf + 5][lrow] = av1.y;
        As[lhalf + 6][lrow] = av1.z; As[lhalf + 7][lrow] = av1.w;
        Ws[wkk * 4 + 0][wjl] = wv.x; Ws[wkk * 4 + 1][wjl] = wv.y;
        Ws[wkk * 4 + 2][wjl] = wv.z; Ws[wkk * 4 + 3][wjl] = wv.w;
        __syncthreads();
        #pragma unroll
        for (int k = 0; k < BK; ++k) {
            float a[8], w[4];
            *(float4*)&a[0] = *(const float4*)&As[k][ty * 8];
            *(float4*)&a[4] = *(const float4*)&As[k][ty * 8 + 4];
            *(float4*)&w[0] = *(const float4*)&Ws[k][tx * 4];
            #pragma unroll
            for (int ii = 0; ii < 8; ++ii)
                #pragma unroll
                for (int jj = 0; jj < 4; ++jj)
                    acc[ii][jj] += a[ii] * w[jj];
        }
        __syncthreads();
    }
    #pragma unroll
    for (int ii = 0; ii < 8; ++ii) {
        size_t r = (size_t)(r0 + ty * 8 + ii);
        if (!second) {
            #pragma unroll
            for (int jj = 0; jj < 4; ++jj) {
                int n = n0 + tx * 4 + jj;
                xp[r * Hn + n] = acc[ii][jj] + b11[n];
            }
        } else {
            #pragma unroll
            for (int jj = 0; jj < 4; ++jj) {
                int n = n0 - Hn + tx * 4 + jj;
                h12[r * Hn + n] = tanhf(acc[ii][jj] + c12[n]);
            }
        }
    }
}

// ---------------------------------------------------------------------------
// Dataflow scan v6: self-sequenced 64-bit packets [h1:24|h2:24|seq:16].
// 192 blocks = 8 groups(8 batches) x 24 col-blocks(32 cols), 512 threads.
// No flags, no drain barrier: data word IS the flag (single-copy atomic).
// Consumers spin per-thread on the 12 packets they scatter. 2 barriers/step.
// Weights: 36 bf16 hi/lo B-frags (144 VGPR, cap 256 via launch_bounds(512,1)).
__global__ void __launch_bounds__(512, 1) scan_kernel(
        const float* __restrict__ xp, const float* __restrict__ h12,
        const float* __restrict__ tagx,
        const float* __restrict__ Whh11, const float* __restrict__ Wih21,
        const float* __restrict__ Whh21, const float* __restrict__ b21,
        const float* __restrict__ Wtag,
        float* __restrict__ pub, float* __restrict__ out) {
    __shared__ unsigned short planes[4 * PSZ];   // h1hi,h1lo,h2hi,h2lo  101.4 KB
    __shared__ float redbuf[8][4][64][4];        // 32 KB [wave][acc][lane][reg]
    __shared__ float wt1[Hn], wt2[Hn];           // 6 KB
    __shared__ float tagbuf[8];

    const int tid  = threadIdx.x;
    const int wv   = tid >> 6;          // wave 0..7
    const int lane = tid & 63;
    const int bid  = blockIdx.x;
    const int g    = bid & 7;           // group (XCD round-robin heuristic)
    const int prod = bid >> 3;          // col-block 0..23

    // ---- loop-invariant: B-fragments (hi/lo bf16), 36 frags = 144 VGPR ----
    short8v wb[3][3][2][2];             // [mat][ktl][nt][hi=0/lo=1]
    {
        #pragma unroll
        for (int mt = 0; mt < 3; ++mt) {
            const float* Wmat = (mt == 0) ? Whh11 : (mt == 1) ? Wih21 : Whh21;
            #pragma unroll
            for (int ktl = 0; ktl < 3; ++ktl) {
                #pragma unroll
                for (int nt = 0; nt < 2; ++nt) {
                    int gcol = prod * 32 + nt * 16 + (lane & 15);
                    int k0   = (wv * 3 + ktl) * 32 + (lane >> 4) * 8;
                    const float* p = Wmat + (size_t)gcol * Hn + k0;
                    float4 f0 = *(const float4*)p;
                    float4 f1 = *(const float4*)(p + 4);
                    float fv[8] = {f0.x, f0.y, f0.z, f0.w, f1.x, f1.y, f1.z, f1.w};
                    union { short8v v; unsigned short u[8]; } hi, lo;
                    #pragma unroll
                    for (int i = 0; i < 8; ++i) {
                        unsigned short h = f2bf(fv[i]);
                        hi.u[i] = h;
                        lo.u[i] = f2bf(fv[i] - bf2f(h));
                    }
                    wb[mt][ktl][nt][0] = hi.v;
                    wb[mt][ktl][nt][1] = lo.v;
                }
            }
        }
    }
    for (int i = tid; i < Hn; i += 512) { wt1[i] = Wtag[i]; wt2[i] = Wtag[Hn + i]; }
    const int ecol = prod * 32 + (tid & 31);     // epilogue col for tid<256
    const float bias21 = b21[ecol];

    // zero planes once (rows 8-15 stay zero; rows 0-7 overwritten each step)
    for (int i = tid; i < 4 * PSZ / 2; i += 512) ((unsigned int*)planes)[i] = 0u;

    float* outO   = out;
    float* outH2  = out + RTn;
    float* outTag = out + RTn + (size_t)RTn * Hn;
    float h2c = 0.f;                    // fp32 carry (tid<256)
    __syncthreads();

    for (int t = 0; t < Tn; ++t) {
        // flag-independent prefetch
        float xpv = 0.f, h12pv = 0.f, tgxv = 0.f;
        if (tid < 256) {
            int m = tid >> 5;
            size_t rr = (size_t)(g * 8 + m) * Tn + t;
            xpv   = xp  [rr * Hn + ecol];
            h12pv = h12 [rr * Hn + ecol];
            tgxv  = tagx[rr];
        }

        // spin-gather: each thread owns 12 packets; poll until seq == t
        unsigned long long v[12];
        {
            const unsigned long long* pubc =
                (const unsigned long long*)(pub + (size_t)(t & 3) * SSTR + g * GSTR);
            const unsigned sq = (unsigned)(t & 0xFFFF);
            unsigned pend = 0xFFFu;
            while (pend) {
                #pragma unroll
                for (int i = 0; i < 12; ++i)
                    if (pend & (1u << i))
                        v[i] = __hip_atomic_load(pubc + tid + i * 512,
                                                 __ATOMIC_RELAXED,
                                                 __HIP_MEMORY_SCOPE_AGENT);
                unsigned np = 0;
                #pragma unroll
                for (int i = 0; i < 12; ++i)
                    if ((pend & (1u << i)) &&
                        (unsigned)(v[i] & 0xFFFFull) != sq) np |= (1u << i);
                pend = np;
                if (pend) __builtin_amdgcn_s_sleep(1);
            }
        }
        // scatter: unpack 24-bit h1/h2, split to hi/lo bf16 planes
        #pragma unroll
        for (int i = 0; i < 12; ++i) {
            int idx = tid + i * 512;
            int p = idx >> 8, rem = idx & 255;
            int m = rem >> 5, jc = rem & 31;
            int base = m * PITCH + p * 32 + jc;
            float h1 = bf24((unsigned)((v[i] >> 40) & 0xFFFFFFull));
            float h2 = bf24((unsigned)((v[i] >> 16) & 0xFFFFFFull));
            unsigned short h1h = f2bf(h1);
            unsigned short h1l = f2bf(h1 - bf2f(h1h));
            unsigned short h2h = f2bf(h2);
            unsigned short h2l = f2bf(h2 - bf2f(h2h));
            planes[0 * PSZ + base] = h1h;
            planes[1 * PSZ + base] = h1l;
            planes[2 * PSZ + base] = h2h;
            planes[3 * PSZ + base] = h2l;
        }
        __syncthreads();   // B: planes staged (also protects redbuf reuse)

        // gate: wave wv = batch wv; lane covers k = lane*12 .. +12
        {
            const int kb = lane * 12;
            float s = 0.f;
            #pragma unroll
            for (int part = 0; part < 3; ++part) {
                int off = wv * PITCH + kb + part * 4;
                unsigned long long u1h = *(const unsigned long long*)&planes[0 * PSZ + off];
                unsigned long long u1l = *(const unsigned long long*)&planes[1 * PSZ + off];
                unsigned long long u2h = *(const unsigned long long*)&planes[2 * PSZ + off];
                unsigned long long u2l = *(const unsigned long long*)&planes[3 * PSZ + off];
                #pragma unroll
                for (int e = 0; e < 4; ++e) {
                    int k = kb + part * 4 + e;
                    float h1 = bf2f((unsigned short)(u1h >> (16 * e)))
                             + bf2f((unsigned short)(u1l >> (16 * e)));
                    float h2 = bf2f((unsigned short)(u2h >> (16 * e)))
                             + bf2f((unsigned short)(u2l >> (16 * e)));
                    s = fmaf(h1, wt1[k], s);
                    s = fmaf(h2, wt2[k], s);
                }
            }
            #pragma unroll
            for (int mm = 1; mm < 64; mm <<= 1) s += __shfl_xor(s, mm, 64);
            if (lane == 0) tagbuf[wv] = s;
        }

        // MFMA matvec: wave wv covers K-tiles wv*3..+3
        {
            f32x4 a00 = {0.f,0.f,0.f,0.f}, a01 = {0.f,0.f,0.f,0.f};
            f32x4 a10 = {0.f,0.f,0.f,0.f}, a11v = {0.f,0.f,0.f,0.f};
            const int ar = (lane & 15) * PITCH + (lane >> 4) * 8;
            #pragma unroll
            for (int ktl = 0; ktl < 3; ++ktl) {
                const int ko = (wv * 3 + ktl) * 32 + ar;
                short8v h1h = __builtin_bit_cast(short8v, *(const uint4*)&planes[0 * PSZ + ko]);
                short8v h1l = __builtin_bit_cast(short8v, *(const uint4*)&planes[1 * PSZ + ko]);
                short8v h2h = __builtin_bit_cast(short8v, *(const uint4*)&planes[2 * PSZ + ko]);
                short8v h2l = __builtin_bit_cast(short8v, *(const uint4*)&planes[3 * PSZ + ko]);
                a00 = __builtin_amdgcn_mfma_f32_16x16x32_bf16(h1h, wb[0][ktl][0][0], a00, 0, 0, 0);
                a00 = __builtin_amdgcn_mfma_f32_16x16x32_bf16(h1l, wb[0][ktl][0][0], a00, 0, 0, 0);
                a00 = __builtin_amdgcn_mfma_f32_16x16x32_bf16(h1h, wb[0][ktl][0][1], a00, 0, 0, 0);
                a01 = __builtin_amdgcn_mfma_f32_16x16x32_bf16(h1h, wb[0][ktl][1][0], a01, 0, 0, 0);
                a01 = __builtin_amdgcn_mfma_f32_16x16x32_bf16(h1l, wb[0][ktl][1][0], a01, 0, 0, 0);
                a01 = __builtin_amdgcn_mfma_f32_16x16x32_bf16(h1h, wb[0][ktl][1][1], a01, 0, 0, 0);
                a10 = __builtin_amdgcn_mfma_f32_16x16x32_bf16(h1h, wb[1][ktl][0][0], a10, 0, 0, 0);
                a10 = __builtin_amdgcn_mfma_f32_16x16x32_bf16(h1l, wb[1][ktl][0][0], a10, 0, 0, 0);
                a10 = __builtin_amdgcn_mfma_f32_16x16x32_bf16(h1h, wb[1][ktl][0][1], a10, 0, 0, 0);
                a11v = __builtin_amdgcn_mfma_f32_16x16x32_bf16(h1h, wb[1][ktl][1][0], a11v, 0, 0, 0);
                a11v = __builtin_amdgcn_mfma_f32_16x16x32_bf16(h1l, wb[1][ktl][1][0], a11v, 0, 0, 0);
                a11v = __builtin_amdgcn_mfma_f32_16x16x32_bf16(h1h, wb[1][ktl][1][1], a11v, 0, 0, 0);
                a10 = __builtin_amdgcn_mfma_f32_16x16x32_bf16(h2h, wb[2][ktl][0][0], a10, 0, 0, 0);
                a10 = __builtin_amdgcn_mfma_f32_16x16x32_bf16(h2l, wb[2][ktl][0][0], a10, 0, 0, 0);
                a10 = __builtin_amdgcn_mfma_f32_16x16x32_bf16(h2h, wb[2][ktl][0][1], a10, 0, 0, 0);
                a11v = __builtin_amdgcn_mfma_f32_16x16x32_bf16(h2h, wb[2][ktl][1][0], a11v, 0, 0, 0);
                a11v = __builtin_amdgcn_mfma_f32_16x16x32_bf16(h2l, wb[2][ktl][1][0], a11v, 0, 0, 0);
                a11v = __builtin_amdgcn_mfma_f32_16x16x32_bf16(h2h, wb[2][ktl][1][1], a11v, 0, 0, 0);
            }
            *(f32x4*)&redbuf[wv][0][lane][0] = a00;
            *(f32x4*)&redbuf[wv][1][lane][0] = a01;
            *(f32x4*)&redbuf[wv][2][lane][0] = a10;
            *(f32x4*)&redbuf[wv][3][lane][0] = a11v;
        }
        __syncthreads();   // C: redbuf + tagbuf ready

        // epilogue: tid<256 = (batch m, col jc); single-packet publish
        float o = 0.f, tg = 0.f, h2nv = 0.f;
        if (tid < 256) {
            int m = tid >> 5, jc = tid & 31;
            int n = jc & 15, nt = jc >> 4;
            int rl = (m >> 2) * 16 + n, rg = m & 3;
            float f11 = 0.f, f21 = 0.f;
            #pragma unroll
            for (int w = 0; w < 8; ++w) {
                f11 += redbuf[w][nt][rl][rg];
                f21 += redbuf[w][2 + nt][rl][rg];
            }
            tg = tagbuf[m] + tgxv;
            o  = 1.f / (1.f + expf(-tg));
            float h11v = tanhf(xpv + f11);
            float h21v = tanhf(f21 + bias21);
            float h1nv = h11v * (1.f - o) + h12pv * o;
            h2nv = h2c * (1.f - o) + h21v * o;
            h2c = h2nv;
            unsigned long long u = ((unsigned long long)f24(h1nv) << 40)
                                 | ((unsigned long long)f24(h2nv) << 16)
                                 | (unsigned long long)((t + 1) & 0xFFFF);
            unsigned long long* pn =
                (unsigned long long*)(pub + (size_t)((t + 1) & 3) * SSTR + g * GSTR)
                + prod * 256 + m * 32 + jc;
            __hip_atomic_store(pn, u, __ATOMIC_RELAXED, __HIP_MEMORY_SCOPE_AGENT);
            // outputs (not on the inter-block critical chain)
            size_t rr = (size_t)(g * 8 + m) * Tn + t;
            outH2[rr * Hn + ecol] = h2nv;
            if (jc == 0 && prod == 0) { outO[rr] = o; outTag[rr] = tg; }
        }
    }
}

// ---------------------------------------------------------------------------
extern "C" void kernel_launch(void* const* d_in, const int* in_sizes, int n_in,
                              void* d_out, int out_size, void* d_ws, size_t ws_size,
                              hipStream_t stream) {
    const float* bert  = (const float*)d_in[0];
    const float* Wih11 = (const float*)d_in[1];
    const float* Whh11 = (const float*)d_in[2];
    const float* b11   = (const float*)d_in[3];
    const float* Wih12 = (const float*)d_in[4];
    const float* Whh12 = (const float*)d_in[5];
    const float* b12   = (const float*)d_in[6];
    const float* Wih21 = (const float*)d_in[7];
    const float* Whh21 = (const float*)d_in[8];
    const float* b21   = (const float*)d_in[9];
    const float* Wtag  = (const float*)d_in[10];
    const float* btag  = (const float*)d_in[11];
    const float* hinit = (const float*)d_in[12];
    float* ws = (float*)d_ws;
    float* xp    = ws + OFF_XP;
    float* h12   = ws + OFF_H12;
    float* tagx  = ws + OFF_TAGX;
    float* c12   = ws + OFF_C12;
    float* pub   = ws + OFF_PUB;
    float* out   = (float*)d_out;

    // zero publish ring: slot 0 becomes the initial state (h=0, seq=0)
    hipMemsetAsync(pub, 0, (size_t)SLOTS * SSTR * sizeof(float), stream);

    c12_kernel<<<3, 256, 0, stream>>>(Whh12, hinit, b12, c12);
    gemm_pre<<<256 * 24, 256, 0, stream>>>(bert, Wih11, Wih12, b11, c12, xp, h12);
    tagx_kernel<<<RTn / 4, 256, 0, stream>>>(bert, Wtag, btag, tagx);

    void* params[] = { &xp, &h12, &tagx, &Whh11, &Wih21, &Whh21, &b21, &Wtag,
                       &pub, &out };
    hipLaunchCooperativeKernel((void*)scan_kernel, dim3(192), dim3(512),
                               params, 0, stream);
}